// Round 15
// baseline (312.740 us; speedup 1.0000x reference)
//
#include <hip/hip_runtime.h>
#include <stdint.h>

#define BB 4
#define SEQ 2048
#define DMODEL 1024
#define NHEAD 16
#define HDIM 64
#define INTER 1024
// attn scale folded into q at GEMM1 epilogue, with log2(e) so softmax is exp2:
// 0.03125 * 1.4426950408889634
#define QSCALE 0.045084220027780106f

#if __has_builtin(__builtin_amdgcn_exp2f)
#define EXP2F(x) __builtin_amdgcn_exp2f(x)
#else
#define EXP2F(x) exp2f(x)
#endif

typedef unsigned short u16;
typedef __attribute__((ext_vector_type(4))) unsigned short u16x4;
typedef __attribute__((ext_vector_type(4))) short s16x4;
typedef __attribute__((ext_vector_type(8))) short s16x8;   // 8 bf16 (4 VGPRs) MFMA A/B frag
typedef __attribute__((ext_vector_type(4))) float f32x4;
typedef __attribute__((ext_vector_type(16))) float f32x16; // 32x32 MFMA C/D frag
typedef __attribute__((ext_vector_type(4))) unsigned int u32x4;

__device__ __forceinline__ u16 f2bf(float f) {
  unsigned int u = __float_as_uint(f);
  u += 0x7FFFu + ((u >> 16) & 1u);   // RNE
  return (u16)(u >> 16);
}

// pack 2 fp32 -> 2 bf16 in one dword (lo = a, hi = b)
#if __has_builtin(__builtin_amdgcn_cvt_pk_bf16_f32)
typedef __attribute__((ext_vector_type(2))) __bf16 bf16x2_t;
__device__ __forceinline__ unsigned int pk2bf(float a, float b) {
  bf16x2_t r = __builtin_amdgcn_cvt_pk_bf16_f32(a, b);
  return *reinterpret_cast<unsigned int*>(&r);
}
#else
__device__ __forceinline__ unsigned int pk2bf(float a, float b) {
  return (unsigned int)f2bf(a) | ((unsigned int)f2bf(b) << 16);
}
#endif

// async global->LDS, 16B per lane; LDS dest is wave-uniform base + lane*16
__device__ __forceinline__ void async16(const u16* g, u16* l) {
  __builtin_amdgcn_global_load_lds((__attribute__((address_space(1))) void*)(void*)(g),
                                   (__attribute__((address_space(3))) void*)(l),
                                   16, 0, 0);
}

// Half of the P redistribution: build ONE PV B-fragment from 4 packed dwords.
// (Split form of the verified make_pb -- halves the transient register peak.)
__device__ __forceinline__ s16x8 make_pb_half(unsigned c0, unsigned c1,
                                              unsigned c2, unsigned c3, int half) {
#if __has_builtin(__builtin_amdgcn_permlane32_swap)
  (void)half;
  auto ra = __builtin_amdgcn_permlane32_swap(c0, c2, false, false);
  auto rb = __builtin_amdgcn_permlane32_swap(c1, c3, false, false);
  u32x4 w = {(unsigned)ra[0], (unsigned)rb[0], (unsigned)ra[1], (unsigned)rb[1]};
#else
  unsigned x0 = __shfl_xor((int)c0, 32, 64), x1 = __shfl_xor((int)c1, 32, 64);
  unsigned x2 = __shfl_xor((int)c2, 32, 64), x3 = __shfl_xor((int)c3, 32, 64);
  u32x4 w = {half ? x2 : c0, half ? x3 : c1, half ? c2 : x0, half ? c3 : x1};
#endif
  return *reinterpret_cast<s16x8*>(&w);
}

// ------------- prep v2a: cast features, 32 B per thread -------------
__global__ __launch_bounds__(256) void featcast(const float* __restrict__ f,
                                                u16* __restrict__ Xb) {
  const int i = (blockIdx.x * 256 + threadIdx.x) * 8;
  f32x4 a = *reinterpret_cast<const f32x4*>(f + i);
  f32x4 b = *reinterpret_cast<const f32x4*>(f + i + 4);
  uint4 o;
  o.x = pk2bf(a[0], a[1]);
  o.y = pk2bf(a[2], a[3]);
  o.z = pk2bf(b[0], b[1]);
  o.w = pk2bf(b[2], b[3]);
  *reinterpret_cast<uint4*>(Xb + i) = o;
}

// ------------- prep v2b: transpose-cast both weights, 64x64 tiles -------------
__global__ __launch_bounds__(256) void wtrans(
    const float* __restrict__ wqkv, const float* __restrict__ wout,
    u16* __restrict__ WqkvT, u16* __restrict__ WoutT) {
  __shared__ u16 tile[64][65];
  int t = blockIdx.x;
  const float* src; u16* dst; int rows, cols, bx, by;
  if (t < 768) {                          // W_qkv: [1024][3072] -> [3072][1024]
    src = wqkv; dst = WqkvT; rows = DMODEL; cols = 3 * INTER;
    bx = t % 48; by = t / 48;
  } else {                                // W_out: [1024][1024] -> [1024][1024]
    t -= 768;
    src = wout; dst = WoutT; rows = INTER; cols = DMODEL;
    bx = t & 15; by = t >> 4;
  }
  const int c0 = bx * 64, r0 = by * 64;
  const int tx = threadIdx.x & 63, ty = threadIdx.x >> 6;
  #pragma unroll
  for (int i = ty; i < 64; i += 4)
    tile[i][tx] = f2bf(src[(size_t)(r0 + i) * cols + c0 + tx]);
  __syncthreads();
  #pragma unroll
  for (int i = ty; i < 64; i += 4)
    dst[(size_t)(c0 + i) * rows + r0 + tx] = tile[tx][i];
}

// ---------------- bf16 GEMM, B-transposed input (round-6, known-good) ----------------
#define GCOMP(ABUF, BBUF)                                                         \
  {                                                                               \
    s16x8 af[4], bf[4];                                                           \
    _Pragma("unroll")                                                             \
    for (int t = 0; t < 4; t++) {                                                 \
      af[t] = *reinterpret_cast<const s16x8*>(&ABUF[(wr + t * 16 + r) * 32 + q8]); \
      bf[t] = *reinterpret_cast<const s16x8*>(&BBUF[(wc + t * 16 + r) * 32 + q8]); \
    }                                                                             \
    _Pragma("unroll")                                                             \
    for (int i = 0; i < 4; i++)                                                   \
      _Pragma("unroll")                                                           \
      for (int j = 0; j < 4; j++)                                                 \
        acc[i][j] = __builtin_amdgcn_mfma_f32_16x16x32_bf16(af[i], bf[j], acc[i][j], 0, 0, 0); \
  }

template <int MODE>
__global__ __launch_bounds__(256, 2) void gemm_bt(
    const u16* __restrict__ A, const u16* __restrict__ BT,
    float* __restrict__ Cf, u16* __restrict__ Qb, u16* __restrict__ Kp,
    u16* __restrict__ Vp, int K, int ldc) {
  __shared__ u16 As[2][128 * 32];
  __shared__ u16 Bs[2][128 * 32];
  const int tid = threadIdx.x;
  const int wave = tid >> 6, lane = tid & 63;
  const int row0 = blockIdx.y * 128, col0 = blockIdx.x * 128;
  const int wr = (wave >> 1) * 64, wc = (wave & 1) * 64;
  const int r = lane & 15, q8 = (lane >> 4) * 8;

  f32x4 acc[4][4] = {};

  const int sRow = lane >> 2, sK = (lane & 3) * 8;
  const u16* Ag0 = A + (size_t)(row0 + wave * 32 + sRow) * K + sK;
  const u16* Ag1 = Ag0 + (size_t)16 * K;
  const u16* Bg0 = BT + (size_t)(col0 + wave * 32 + sRow) * K + sK;
  const u16* Bg1 = Bg0 + (size_t)16 * K;
  u16* Al0a = &As[0][wave * 1024]; u16* Al1a = Al0a + 512;
  u16* Bl0a = &Bs[0][wave * 1024]; u16* Bl1a = Bl0a + 512;
  u16* Al0b = &As[1][wave * 1024]; u16* Al1b = Al0b + 512;
  u16* Bl0b = &Bs[1][wave * 1024]; u16* Bl1b = Bl0b + 512;

  // prologue: stage K-tile 0 into buffer A
  async16(Ag0, Al0a);
  async16(Ag1, Al1a);
  async16(Bg0, Bl0a);
  async16(Bg1, Bl1a);
  __syncthreads();

  for (int k0 = 0; k0 < K; k0 += 64) {
    if (k0 + 32 < K) {
      async16(Ag0 + k0 + 32, Al0b);
      async16(Ag1 + k0 + 32, Al1b);
      async16(Bg0 + k0 + 32, Bl0b);
      async16(Bg1 + k0 + 32, Bl1b);
    }
    GCOMP(As[0], Bs[0])
    __syncthreads();
    if (k0 + 64 < K) {
      async16(Ag0 + k0 + 64, Al0a);
      async16(Ag1 + k0 + 64, Al1a);
      async16(Bg0 + k0 + 64, Bl0a);
      async16(Bg1 + k0 + 64, Bl1a);
    }
    GCOMP(As[1], Bs[1])
    __syncthreads();
  }

  const int quad = lane >> 4;
  #pragma unroll
  for (int i = 0; i < 4; i++) {
    const int n = row0 + wr + i * 16 + quad * 4;   // global row for regs 0..3
    const int b = n >> 11, nn = n & (SEQ - 1);
    #pragma unroll
    for (int j = 0; j < 4; j++) {
      const int gc = col0 + wc + j * 16 + r;       // wave-uniform region
      if (MODE == 1) {
        #pragma unroll
        for (int reg = 0; reg < 4; reg++)
          Cf[(size_t)(n + reg) * ldc + gc] = acc[i][j][reg];
      } else if (gc < INTER) {                     // q: row-major, scaled
        size_t base = (size_t)n * INTER + gc;
        #pragma unroll
        for (int reg = 0; reg < 4; reg++)
          Qb[base + (size_t)reg * INTER] = f2bf(acc[i][j][reg] * QSCALE);
      } else if (gc < 2 * INTER) {                 // k -> Kp packed
        int dim = gc - INTER, h = dim >> 6, d = dim & 63;
        int bh = b * NHEAD + h;
        size_t base = (((size_t)(bh * 64 + (nn >> 5)) * 4 + (d >> 4)) * 64 +
                       ((((d >> 3) & 1) << 5) | (nn & 31))) * 8 + (d & 7);
        #pragma unroll
        for (int reg = 0; reg < 4; reg++)
          Kp[base + reg * 8] = f2bf(acc[i][j][reg]);
      } else {                                     // v -> Vp packed, b64 store
        int dim = gc - 2 * INTER, h = dim >> 6, d = dim & 63;
        int bh = b * NHEAD + h;
        size_t base = ((((size_t)(bh * 64 + (nn >> 5)) * 2 + ((nn >> 4) & 1)) * 2 +
                        (d >> 5)) * 64 +
                       ((((nn >> 3) & 1) << 5) | (d & 31))) * 8 + (nn & 7);
        uint2 pk;
        pk.x = pk2bf(acc[i][j][0], acc[i][j][1]);
        pk.y = pk2bf(acc[i][j][2], acc[i][j][3]);
        *reinterpret_cast<uint2*>(Vp + base) = pk;
      }
    }
  }
}

// ---------------- flash-style attention: slim pipelined step, 4 waves/SIMD ----------------
// Round-14 finding: 128-thread packing did NOT raise occupancy (24.7% at any
// block shape) -> VGPR allocation is granular (64/128/256 steps, m69): our
// ~160-VGPR wave allocates a 256-slot = 2 waves/SIMD ceiling. This round fits
// the PIPELINED step in <=128 VGPR for 4 waves/SIMD (the one untested cell;
// round-3's spill was peak-live ~144 from full vf[4]+cc[8] transients):
//  (1) single K buffer kf[16 regs]: QK(j+1) MFMAs consume kf, THEN the
//      K(j+2) loads redefine it -- live ranges disjoint in schedule order,
//      regalloc reuses the slots; prefetch distance stays ~1 full step.
//  (2) split softmax/PV: (q=0,1 -> pb0 -> PV vf0,vf1) then (q=2,3 -> pb1 ->
//      PV vf2,vf3) -- transient peak 32 -> ~16 regs.
// Persistent: qf16 + kf16 + stA16 + stB16 + ot32 = 96; peak ~122 < 128.
// __launch_bounds__(64,4) = the 128 cap. SPILL GATE: WRITE_SIZE must stay
// ~16.4 MB; if it balloons, this cell is infeasible and round-6 attn is final.
// grid: (bh=64, iblk=64); blockIdx.x = bh keeps XCD = bh%8 (8 heads/XCD L2).
// S^T = K.Q^T via 32x32x16 MFMA; q pre-scaled by SCALE*log2e -> p = exp2(s);
// no max-shift. P->PV redistribution in-register (permlane32_swap halves).
#define PSTEPS(SCUR, SNXT)                                                        \
  {                                                                               \
    /* QK(j+1) from kf (loaded last step) */                                      \
    __builtin_amdgcn_s_setprio(1);                                                \
    SNXT = (f32x16){};                                                            \
    _Pragma("unroll")                                                             \
    for (int c = 0; c < 4; c++)                                                   \
      SNXT = __builtin_amdgcn_mfma_f32_32x32x16_bf16(kf[c], qf[c], SNXT, 0, 0, 0); \
    __builtin_amdgcn_s_setprio(0);                                                \
    /* redefine kf <- K(j+2); old kf died at the MFMAs above */                   \
    _Pragma("unroll")                                                             \
    for (int c = 0; c < 4; c++)                                                   \
      kf[c] = *reinterpret_cast<const s16x8*>(kc + c * 512);                      \
    kc += 2048;                                                                   \
    /* softmax q=0,1 -> pb0 -> PV with vf0,vf1 */                                 \
    {                                                                             \
      float p0 = EXP2F(SCUR[0]), p1 = EXP2F(SCUR[1]);                             \
      float p2 = EXP2F(SCUR[2]), p3 = EXP2F(SCUR[3]);                             \
      float p4 = EXP2F(SCUR[4]), p5 = EXP2F(SCUR[5]);                             \
      float p6 = EXP2F(SCUR[6]), p7 = EXP2F(SCUR[7]);                             \
      ls += ((p0 + p1) + (p2 + p3)) + ((p4 + p5) + (p6 + p7));                    \
      s16x8 pb0 = make_pb_half(pk2bf(p0, p1), pk2bf(p2, p3),                      \
                               pk2bf(p4, p5), pk2bf(p6, p7), half);               \
      s16x8 vf0 = *reinterpret_cast<const s16x8*>(vc);                            \
      s16x8 vf1 = *reinterpret_cast<const s16x8*>(vc + 512);                      \
      __builtin_amdgcn_s_setprio(1);                                              \
      ot0 = __builtin_amdgcn_mfma_f32_32x32x16_bf16(vf0, pb0, ot0, 0, 0, 0);      \
      ot1 = __builtin_amdgcn_mfma_f32_32x32x16_bf16(vf1, pb0, ot1, 0, 0, 0);      \
      __builtin_amdgcn_s_setprio(0);                                              \
    }                                                                             \
    /* softmax q=2,3 -> pb1 -> PV with vf2,vf3 */                                 \
    {                                                                             \
      float p0 = EXP2F(SCUR[8]), p1 = EXP2F(SCUR[9]);                             \
      float p2 = EXP2F(SCUR[10]), p3 = EXP2F(SCUR[11]);                           \
      float p4 = EXP2F(SCUR[12]), p5 = EXP2F(SCUR[13]);                           \
      float p6 = EXP2F(SCUR[14]), p7 = EXP2F(SCUR[15]);                           \
      ls += ((p0 + p1) + (p2 + p3)) + ((p4 + p5) + (p6 + p7));                    \
      s16x8 pb1 = make_pb_half(pk2bf(p0, p1), pk2bf(p2, p3),                      \
                               pk2bf(p4, p5), pk2bf(p6, p7), half);               \
      s16x8 vf2 = *reinterpret_cast<const s16x8*>(vc + 1024);                     \
      s16x8 vf3 = *reinterpret_cast<const s16x8*>(vc + 1536);                     \
      vc += 2048;                                                                 \
      __builtin_amdgcn_s_setprio(1);                                              \
      ot0 = __builtin_amdgcn_mfma_f32_32x32x16_bf16(vf2, pb1, ot0, 0, 0, 0);      \
      ot1 = __builtin_amdgcn_mfma_f32_32x32x16_bf16(vf3, pb1, ot1, 0, 0, 0);      \
      __builtin_amdgcn_s_setprio(0);                                              \
    }                                                                             \
  }

__global__ __launch_bounds__(64, 4) void attn_kernel(
    const u16* __restrict__ Qb, const u16* __restrict__ Kp,
    const u16* __restrict__ Vp, u16* __restrict__ AO) {
  const int lane = threadIdx.x;
  const int l31 = lane & 31, half = lane >> 5;
  const int bh = blockIdx.x, b = bh >> 4, h = bh & 15;
  const int i0 = blockIdx.y * 32;

  const u16* qbase = Qb + (size_t)(b * SEQ + i0 + l31) * INTER + h * HDIM + half * 8;
  s16x8 qf[4];
  #pragma unroll
  for (int c = 0; c < 4; c++) qf[c] = *reinterpret_cast<const s16x8*>(qbase + c * 16);

  const u16* kc = Kp + (size_t)bh * (64 * 2048) + lane * 8;   // K cursor
  const u16* vc = Vp + (size_t)bh * (64 * 2048) + lane * 8;   // V cursor

  f32x16 ot0 = {}, ot1 = {};
  float ls = 0.f;

  // Prologue: kf=K(0); stA=S(0); kf=K(1); cursors: kc->K(2), vc->V(0).
  s16x8 kf[4];
  #pragma unroll
  for (int c = 0; c < 4; c++)
    kf[c] = *reinterpret_cast<const s16x8*>(kc + c * 512);
  kc += 2048;
  f32x16 stA = {}, stB;
  #pragma unroll
  for (int c = 0; c < 4; c++)
    stA = __builtin_amdgcn_mfma_f32_32x32x16_bf16(kf[c], qf[c], stA, 0, 0, 0);
  #pragma unroll
  for (int c = 0; c < 4; c++)
    kf[c] = *reinterpret_cast<const s16x8*>(kc + c * 512);
  kc += 2048;

  // Loop invariant at step j: stA=S(j), kf=K(j+1), kc->K(j+2), vc->V(j).
  for (int jb = 0; jb < 64; jb += 2) {
    PSTEPS(stA, stB)   // consume S(j);   produce S(j+1); kf <- K(j+2)
    PSTEPS(stB, stA)   // consume S(j+1); produce S(j+2); kf <- K(j+3)
  }
  // Tail: last step's K prefetch reads <=8 KB past Kp[bh] (into the adjacent
  // Vp region -- allocated, dead). Final SNXT is dead (4 wasted MFMAs).

  ls += __shfl_xor(ls, 32, 64);      // lanes L, L+32 hold complementary j-halves
  float rinv = 1.0f / ls;

  u16* orow = AO + (size_t)(b * SEQ + i0 + l31) * INTER + h * HDIM;
  #pragma unroll
  for (int dt = 0; dt < 2; dt++) {
    const f32x16& o = dt ? ot1 : ot0;
    #pragma unroll
    for (int q = 0; q < 4; q++) {
      uint2 pk;
      pk.x = pk2bf(o[q * 4 + 0] * rinv, o[q * 4 + 1] * rinv);
      pk.y = pk2bf(o[q * 4 + 2] * rinv, o[q * 4 + 3] * rinv);
      *reinterpret_cast<uint2*>(orow + dt * 32 + q * 8 + half * 4) = pk;
    }
  }
}

extern "C" void kernel_launch(void* const* d_in, const int* in_sizes, int n_in,
                              void* d_out, int out_size, void* d_ws, size_t ws_size,
                              hipStream_t stream) {
  const float* features = (const float*)d_in[0];
  const float* W_qkv    = (const float*)d_in[1];
  const float* W_out    = (const float*)d_in[2];
  float* out = (float*)d_out;
  char* w = (char*)d_ws;
  u16* Xb    = (u16*)(w);              // [8192][1024] bf16 features      16 MB
  u16* WqkvT = (u16*)(w + 16777216);   // [3072][1024] bf16 W_qkv^T        6 MB
  u16* WoutT = (u16*)(w + 23068672);   // [1024][1024] bf16 W_out^T        2 MB
  u16* Qb    = (u16*)(w + 25165824);   // [8192][1024] bf16 q (scaled)    16 MB
  u16* Kp    = (u16*)(w + 41943040);   // fragment-packed K               16 MB
  u16* Vp    = (u16*)(w + 58720256);   // fragment-packed V               16 MB
  u16* AO    = Xb;                     // attn out OVERLAYS Xb (Xb dead after
                                       // gemm0; stream-ordered)

  featcast<<<dim3(4096), dim3(256), 0, stream>>>(features, Xb);
  wtrans<<<dim3(1024), dim3(256), 0, stream>>>(W_qkv, W_out, WqkvT, WoutT);
  gemm_bt<0><<<dim3(24, 64), dim3(256), 0, stream>>>(Xb, WqkvT, nullptr, Qb, Kp, Vp,
                                                     DMODEL, 0);
  attn_kernel<<<dim3(64, 64), dim3(64), 0, stream>>>(Qb, Kp, Vp, AO);
  gemm_bt<1><<<dim3(8, 64), dim3(256), 0, stream>>>(AO, WoutT, out, nullptr, nullptr,
                                                    nullptr, INTER, DMODEL);
}

// Round 16
// 281.730 us; speedup vs baseline: 1.1101x; 1.1101x over previous
//
#include <hip/hip_runtime.h>
#include <stdint.h>

#define BB 4
#define SEQ 2048
#define DMODEL 1024
#define NHEAD 16
#define HDIM 64
#define INTER 1024
// attn scale folded into q at GEMM1 epilogue, with log2(e) so softmax is exp2:
// 0.03125 * 1.4426950408889634
#define QSCALE 0.045084220027780106f

#if __has_builtin(__builtin_amdgcn_exp2f)
#define EXP2F(x) __builtin_amdgcn_exp2f(x)
#else
#define EXP2F(x) exp2f(x)
#endif

typedef unsigned short u16;
typedef __attribute__((ext_vector_type(4))) unsigned short u16x4;
typedef __attribute__((ext_vector_type(4))) short s16x4;
typedef __attribute__((ext_vector_type(8))) short s16x8;   // 8 bf16 (4 VGPRs) MFMA A/B frag
typedef __attribute__((ext_vector_type(4))) float f32x4;
typedef __attribute__((ext_vector_type(16))) float f32x16; // 32x32 MFMA C/D frag
typedef __attribute__((ext_vector_type(4))) unsigned int u32x4;

__device__ __forceinline__ u16 f2bf(float f) {
  unsigned int u = __float_as_uint(f);
  u += 0x7FFFu + ((u >> 16) & 1u);   // RNE
  return (u16)(u >> 16);
}

// pack 2 fp32 -> 2 bf16 in one dword (lo = a, hi = b)
#if __has_builtin(__builtin_amdgcn_cvt_pk_bf16_f32)
typedef __attribute__((ext_vector_type(2))) __bf16 bf16x2_t;
__device__ __forceinline__ unsigned int pk2bf(float a, float b) {
  bf16x2_t r = __builtin_amdgcn_cvt_pk_bf16_f32(a, b);
  return *reinterpret_cast<unsigned int*>(&r);
}
#else
__device__ __forceinline__ unsigned int pk2bf(float a, float b) {
  return (unsigned int)f2bf(a) | ((unsigned int)f2bf(b) << 16);
}
#endif

// async global->LDS, 16B per lane; LDS dest is wave-uniform base + lane*16
__device__ __forceinline__ void async16(const u16* g, u16* l) {
  __builtin_amdgcn_global_load_lds((__attribute__((address_space(1))) void*)(void*)(g),
                                   (__attribute__((address_space(3))) void*)(l),
                                   16, 0, 0);
}

// Redistribute P into the two PV B-fragments fully in-register.
// Correctness-verified in the harness (absmax identical to the LDS path).
__device__ __forceinline__ void make_pb(const unsigned int* cc, int half,
                                        s16x8& pb0, s16x8& pb1) {
#if __has_builtin(__builtin_amdgcn_permlane32_swap)
  (void)half;
  auto r02 = __builtin_amdgcn_permlane32_swap(cc[0], cc[2], false, false);
  auto r13 = __builtin_amdgcn_permlane32_swap(cc[1], cc[3], false, false);
  auto r46 = __builtin_amdgcn_permlane32_swap(cc[4], cc[6], false, false);
  auto r57 = __builtin_amdgcn_permlane32_swap(cc[5], cc[7], false, false);
  u32x4 w0 = {(unsigned)r02[0], (unsigned)r13[0], (unsigned)r02[1], (unsigned)r13[1]};
  u32x4 w1 = {(unsigned)r46[0], (unsigned)r57[0], (unsigned)r46[1], (unsigned)r57[1]};
#else
  unsigned x0 = __shfl_xor((int)cc[0], 32, 64), x1 = __shfl_xor((int)cc[1], 32, 64);
  unsigned x2 = __shfl_xor((int)cc[2], 32, 64), x3 = __shfl_xor((int)cc[3], 32, 64);
  unsigned x4 = __shfl_xor((int)cc[4], 32, 64), x5 = __shfl_xor((int)cc[5], 32, 64);
  unsigned x6 = __shfl_xor((int)cc[6], 32, 64), x7 = __shfl_xor((int)cc[7], 32, 64);
  u32x4 w0 = {half ? x2 : cc[0], half ? x3 : cc[1],
              half ? cc[2] : x0, half ? cc[3] : x1};
  u32x4 w1 = {half ? x6 : cc[4], half ? x7 : cc[5],
              half ? cc[6] : x4, half ? cc[7] : x5};
#endif
  pb0 = *reinterpret_cast<s16x8*>(&w0);
  pb1 = *reinterpret_cast<s16x8*>(&w1);
}

// ------------- prep v2a: cast features, 32 B per thread -------------
__global__ __launch_bounds__(256) void featcast(const float* __restrict__ f,
                                                u16* __restrict__ Xb) {
  const int i = (blockIdx.x * 256 + threadIdx.x) * 8;
  f32x4 a = *reinterpret_cast<const f32x4*>(f + i);
  f32x4 b = *reinterpret_cast<const f32x4*>(f + i + 4);
  uint4 o;
  o.x = pk2bf(a[0], a[1]);
  o.y = pk2bf(a[2], a[3]);
  o.z = pk2bf(b[0], b[1]);
  o.w = pk2bf(b[2], b[3]);
  *reinterpret_cast<uint4*>(Xb + i) = o;
}

// ------------- prep v2b: transpose-cast both weights, 64x64 tiles -------------
__global__ __launch_bounds__(256) void wtrans(
    const float* __restrict__ wqkv, const float* __restrict__ wout,
    u16* __restrict__ WqkvT, u16* __restrict__ WoutT) {
  __shared__ u16 tile[64][65];
  int t = blockIdx.x;
  const float* src; u16* dst; int rows, cols, bx, by;
  if (t < 768) {                          // W_qkv: [1024][3072] -> [3072][1024]
    src = wqkv; dst = WqkvT; rows = DMODEL; cols = 3 * INTER;
    bx = t % 48; by = t / 48;
  } else {                                // W_out: [1024][1024] -> [1024][1024]
    t -= 768;
    src = wout; dst = WoutT; rows = INTER; cols = DMODEL;
    bx = t & 15; by = t >> 4;
  }
  const int c0 = bx * 64, r0 = by * 64;
  const int tx = threadIdx.x & 63, ty = threadIdx.x >> 6;
  #pragma unroll
  for (int i = ty; i < 64; i += 4)
    tile[i][tx] = f2bf(src[(size_t)(r0 + i) * cols + c0 + tx]);
  __syncthreads();
  #pragma unroll
  for (int i = ty; i < 64; i += 4)
    dst[(size_t)(c0 + i) * rows + r0 + tx] = tile[tx][i];
}

// ---------------- bf16 GEMM, B-transposed input (round-6, known-good) ----------------
// 2-phase double-buffered K-loop. MODE 0: q -> Qb row-major (scaled); k -> Kp
// fragment-packed; v -> Vp fragment-packed (b64 store). MODE 1: C -> fp32 Cf.
// (8-phase 256^2 tested r8/r9: slower at this problem size -- short K,
// 1 block/CU grid tail. This structure is the measured optimum here.)
#define GCOMP(ABUF, BBUF)                                                         \
  {                                                                               \
    s16x8 af[4], bf[4];                                                           \
    _Pragma("unroll")                                                             \
    for (int t = 0; t < 4; t++) {                                                 \
      af[t] = *reinterpret_cast<const s16x8*>(&ABUF[(wr + t * 16 + r) * 32 + q8]); \
      bf[t] = *reinterpret_cast<const s16x8*>(&BBUF[(wc + t * 16 + r) * 32 + q8]); \
    }                                                                             \
    _Pragma("unroll")                                                             \
    for (int i = 0; i < 4; i++)                                                   \
      _Pragma("unroll")                                                           \
      for (int j = 0; j < 4; j++)                                                 \
        acc[i][j] = __builtin_amdgcn_mfma_f32_16x16x32_bf16(af[i], bf[j], acc[i][j], 0, 0, 0); \
  }

template <int MODE>
__global__ __launch_bounds__(256, 2) void gemm_bt(
    const u16* __restrict__ A, const u16* __restrict__ BT,
    float* __restrict__ Cf, u16* __restrict__ Qb, u16* __restrict__ Kp,
    u16* __restrict__ Vp, int K, int ldc) {
  __shared__ u16 As[2][128 * 32];
  __shared__ u16 Bs[2][128 * 32];
  const int tid = threadIdx.x;
  const int wave = tid >> 6, lane = tid & 63;
  const int row0 = blockIdx.y * 128, col0 = blockIdx.x * 128;
  const int wr = (wave >> 1) * 64, wc = (wave & 1) * 64;
  const int r = lane & 15, q8 = (lane >> 4) * 8;

  f32x4 acc[4][4] = {};

  const int sRow = lane >> 2, sK = (lane & 3) * 8;
  const u16* Ag0 = A + (size_t)(row0 + wave * 32 + sRow) * K + sK;
  const u16* Ag1 = Ag0 + (size_t)16 * K;
  const u16* Bg0 = BT + (size_t)(col0 + wave * 32 + sRow) * K + sK;
  const u16* Bg1 = Bg0 + (size_t)16 * K;
  u16* Al0a = &As[0][wave * 1024]; u16* Al1a = Al0a + 512;
  u16* Bl0a = &Bs[0][wave * 1024]; u16* Bl1a = Bl0a + 512;
  u16* Al0b = &As[1][wave * 1024]; u16* Al1b = Al0b + 512;
  u16* Bl0b = &Bs[1][wave * 1024]; u16* Bl1b = Bl0b + 512;

  // prologue: stage K-tile 0 into buffer A
  async16(Ag0, Al0a);
  async16(Ag1, Al1a);
  async16(Bg0, Bl0a);
  async16(Bg1, Bl1a);
  __syncthreads();

  for (int k0 = 0; k0 < K; k0 += 64) {
    if (k0 + 32 < K) {
      async16(Ag0 + k0 + 32, Al0b);
      async16(Ag1 + k0 + 32, Al1b);
      async16(Bg0 + k0 + 32, Bl0b);
      async16(Bg1 + k0 + 32, Bl1b);
    }
    GCOMP(As[0], Bs[0])
    __syncthreads();
    if (k0 + 64 < K) {
      async16(Ag0 + k0 + 64, Al0a);
      async16(Ag1 + k0 + 64, Al1a);
      async16(Bg0 + k0 + 64, Bl0a);
      async16(Bg1 + k0 + 64, Bl1a);
    }
    GCOMP(As[1], Bs[1])
    __syncthreads();
  }

  const int quad = lane >> 4;
  #pragma unroll
  for (int i = 0; i < 4; i++) {
    const int n = row0 + wr + i * 16 + quad * 4;   // global row for regs 0..3
    const int b = n >> 11, nn = n & (SEQ - 1);
    #pragma unroll
    for (int j = 0; j < 4; j++) {
      const int gc = col0 + wc + j * 16 + r;       // wave-uniform region
      if (MODE == 1) {
        #pragma unroll
        for (int reg = 0; reg < 4; reg++)
          Cf[(size_t)(n + reg) * ldc + gc] = acc[i][j][reg];
      } else if (gc < INTER) {                     // q: row-major, scaled
        size_t base = (size_t)n * INTER + gc;
        #pragma unroll
        for (int reg = 0; reg < 4; reg++)
          Qb[base + (size_t)reg * INTER] = f2bf(acc[i][j][reg] * QSCALE);
      } else if (gc < 2 * INTER) {                 // k -> Kp packed
        int dim = gc - INTER, h = dim >> 6, d = dim & 63;
        int bh = b * NHEAD + h;
        size_t base = (((size_t)(bh * 64 + (nn >> 5)) * 4 + (d >> 4)) * 64 +
                       ((((d >> 3) & 1) << 5) | (nn & 31))) * 8 + (d & 7);
        #pragma unroll
        for (int reg = 0; reg < 4; reg++)
          Kp[base + reg * 8] = f2bf(acc[i][j][reg]);
      } else {                                     // v -> Vp packed, b64 store
        int dim = gc - 2 * INTER, h = dim >> 6, d = dim & 63;
        int bh = b * NHEAD + h;
        size_t base = ((((size_t)(bh * 64 + (nn >> 5)) * 2 + ((nn >> 4) & 1)) * 2 +
                        (d >> 5)) * 64 +
                       ((((nn >> 3) & 1) << 5) | (d & 31))) * 8 + (nn & 7);
        uint2 pk;
        pk.x = pk2bf(acc[i][j][0], acc[i][j][1]);
        pk.y = pk2bf(acc[i][j][2], acc[i][j][3]);
        *reinterpret_cast<uint2*>(Vp + base) = pk;
      }
    }
  }
}

// ---------------- flash-style attention (FINAL: round-4/6 config, 94-97 us) ----------------
// 15-round experiment matrix closed: traffic reduction (r2 2x null, r11 4x
// via LDS -21%), occupancy via packing (r14 null -- 256-slot VGPR
// granularity), occupancy via <=128-VGPR diet (r3/r15 spill, -50%), deeper
// V-pipeline (r5 null), instruction diet (r7 null), XCD remap (r1 regression).
// The single win: this T15 2-deep S-pipeline (r4, +6%). The kernel is a
// ~160-VGPR / 2-waves-per-SIMD issue-latency basin.
// grid: (bh=64, iblk=64); blockIdx.x = bh so block->XCD = bh%8 (8 heads =
// 4 MB K/V per XCD-L2). One wave per block, 32 q-rows; no LDS, no barriers.
// T15: QK(j+1) issues BEFORE softmax(j); K prefetched 2 steps ahead.
// S^T = K.Q^T via 32x32x16 MFMA; q pre-scaled by SCALE*log2e -> p = exp2(s);
// no max-shift (scores bounded by construction). P->PV redistribution
// in-register via v_permlane32_swap. setprio(1) wraps MFMA clusters.
#define PSTEP(JCUR, SCUR, SNXT, KNXT, KPF)                                        \
  {                                                                               \
    s16x8 vf[4];                                                                  \
    _Pragma("unroll")                                                             \
    for (int c = 0; c < 4; c++)                                                   \
      vf[c] = *reinterpret_cast<const s16x8*>(vpb + (JCUR) * 2048 + c * 512);     \
    const int jpf = ((JCUR) + 2) & 63;                                            \
    _Pragma("unroll")                                                             \
    for (int c = 0; c < 4; c++)                                                   \
      KPF[c] = *reinterpret_cast<const s16x8*>(kpb + jpf * 2048 + c * 512);       \
    SNXT = (f32x16){};                                                            \
    __builtin_amdgcn_s_setprio(1);                                                \
    _Pragma("unroll")                                                             \
    for (int c = 0; c < 4; c++)                                                   \
      SNXT = __builtin_amdgcn_mfma_f32_32x32x16_bf16(KNXT[c], qf[c], SNXT, 0, 0, 0); \
    __builtin_amdgcn_s_setprio(0);                                                \
    unsigned int cc[8];                                                           \
    _Pragma("unroll")                                                             \
    for (int q = 0; q < 4; q++) {                                                 \
      float p0 = EXP2F(SCUR[q * 4 + 0]), p1 = EXP2F(SCUR[q * 4 + 1]);             \
      float p2 = EXP2F(SCUR[q * 4 + 2]), p3 = EXP2F(SCUR[q * 4 + 3]);             \
      ls += (p0 + p1) + (p2 + p3);                                                \
      cc[q * 2 + 0] = pk2bf(p0, p1);                                              \
      cc[q * 2 + 1] = pk2bf(p2, p3);                                              \
    }                                                                             \
    s16x8 pb0, pb1;                                                               \
    make_pb(cc, half, pb0, pb1);                                                  \
    __builtin_amdgcn_s_setprio(1);                                                \
    ot0 = __builtin_amdgcn_mfma_f32_32x32x16_bf16(vf[0], pb0, ot0, 0, 0, 0);      \
    ot1 = __builtin_amdgcn_mfma_f32_32x32x16_bf16(vf[1], pb0, ot1, 0, 0, 0);      \
    ot0 = __builtin_amdgcn_mfma_f32_32x32x16_bf16(vf[2], pb1, ot0, 0, 0, 0);      \
    ot1 = __builtin_amdgcn_mfma_f32_32x32x16_bf16(vf[3], pb1, ot1, 0, 0, 0);      \
    __builtin_amdgcn_s_setprio(0);                                                \
  }

__global__ __launch_bounds__(64, 3) void attn_kernel(
    const u16* __restrict__ Qb, const u16* __restrict__ Kp,
    const u16* __restrict__ Vp, u16* __restrict__ AO) {
  const int lane = threadIdx.x;
  const int l31 = lane & 31, half = lane >> 5;
  const int bh = blockIdx.x, b = bh >> 4, h = bh & 15;
  const int i0 = blockIdx.y * 32;

  const u16* qbase = Qb + (size_t)(b * SEQ + i0 + l31) * INTER + h * HDIM + half * 8;
  s16x8 qf[4];
  #pragma unroll
  for (int c = 0; c < 4; c++) qf[c] = *reinterpret_cast<const s16x8*>(qbase + c * 16);

  const u16* kpb = Kp + (size_t)bh * (64 * 4 * 512) + lane * 8;
  const u16* vpb = Vp + (size_t)bh * (64 * 4 * 512) + lane * 8;

  f32x16 ot0 = {}, ot1 = {};
  float ls = 0.f;

  s16x8 kX[4], kY[4];
  #pragma unroll
  for (int c = 0; c < 4; c++)
    kX[c] = *reinterpret_cast<const s16x8*>(kpb + 0 * 2048 + c * 512);
  f32x16 stA = {}, stB;
  #pragma unroll
  for (int c = 0; c < 4; c++)
    stA = __builtin_amdgcn_mfma_f32_32x32x16_bf16(kX[c], qf[c], stA, 0, 0, 0);
  #pragma unroll
  for (int c = 0; c < 4; c++)
    kY[c] = *reinterpret_cast<const s16x8*>(kpb + 1 * 2048 + c * 512);

  for (int jb = 0; jb < 64; jb += 2) {
    PSTEP(jb,     stA, stB, kY, kX)
    PSTEP(jb + 1, stB, stA, kX, kY)
  }

  ls += __shfl_xor(ls, 32, 64);
  float rinv = 1.0f / ls;

  u16* orow = AO + (size_t)(b * SEQ + i0 + l31) * INTER + h * HDIM;
  #pragma unroll
  for (int dt = 0; dt < 2; dt++) {
    const f32x16& o = dt ? ot1 : ot0;
    #pragma unroll
    for (int q = 0; q < 4; q++) {
      uint2 pk;
      pk.x = pk2bf(o[q * 4 + 0] * rinv, o[q * 4 + 1] * rinv);
      pk.y = pk2bf(o[q * 4 + 2] * rinv, o[q * 4 + 3] * rinv);
      *reinterpret_cast<uint2*>(orow + dt * 32 + q * 8 + half * 4) = pk;
    }
  }
}

extern "C" void kernel_launch(void* const* d_in, const int* in_sizes, int n_in,
                              void* d_out, int out_size, void* d_ws, size_t ws_size,
                              hipStream_t stream) {
  const float* features = (const float*)d_in[0];
  const float* W_qkv    = (const float*)d_in[1];
  const float* W_out    = (const float*)d_in[2];
  float* out = (float*)d_out;
  char* w = (char*)d_ws;
  u16* Xb    = (u16*)(w);              // [8192][1024] bf16 features      16 MB
  u16* WqkvT = (u16*)(w + 16777216);   // [3072][1024] bf16 W_qkv^T        6 MB
  u16* WoutT = (u16*)(w + 23068672);   // [1024][1024] bf16 W_out^T        2 MB
  u16* Qb    = (u16*)(w + 25165824);   // [8192][1024] bf16 q (scaled)    16 MB
  u16* Kp    = (u16*)(w + 41943040);   // fragment-packed K               16 MB
  u16* Vp    = (u16*)(w + 58720256);   // fragment-packed V               16 MB
  u16* AO    = Xb;                     // attn out OVERLAYS Xb (Xb dead after
                                       // gemm0; stream-ordered)

  featcast<<<dim3(4096), dim3(256), 0, stream>>>(features, Xb);
  wtrans<<<dim3(1024), dim3(256), 0, stream>>>(W_qkv, W_out, WqkvT, WoutT);
  gemm_bt<0><<<dim3(24, 64), dim3(256), 0, stream>>>(Xb, WqkvT, nullptr, Qb, Kp, Vp,
                                                     DMODEL, 0);
  attn_kernel<<<dim3(64, 64), dim3(64), 0, stream>>>(Qb, Kp, Vp, AO);
  gemm_bt<1><<<dim3(8, 64), dim3(256), 0, stream>>>(AO, WoutT, out, nullptr, nullptr,
                                                    nullptr, INTER, DMODEL);
}